// Round 2
// baseline (1511.746 us; speedup 1.0000x reference)
//
#include <hip/hip_runtime.h>

typedef __attribute__((ext_vector_type(4))) float f32x4;
typedef __attribute__((ext_vector_type(8))) short s16x8;

// ---- LDS layout (byte offsets), total 73728 B -> 2 blocks/CU ----
#define L_XW   0        // bf16 [64][256] swz, stride 512B  (later: H chunk, mlp bf16, out stage)
#define L_QK   32768    // bf16 [2][64][64] (q cols 0-31 | k cols 32-63), stride 128B/row, 8192/hh
#define L_VT   49152    // bf16 [2][32][64] v transposed, stride 128B
#define L_P    57344    // bf16 [64][64], stride 128B
#define L_OS   65536    // bf16 [2][64][32] per-head O slice, stride 64B
#define L_Y    32768    // bf16 [64][256] swz, stride 512B (aliases QK/VT/P after attention)
#define L_H    0        // bf16 [64][256] (aliases XW after LN1)
#define L_MB   0        // bf16 [64][256] mlp pre-LN (aliases H after fc2)
#define L_ST   0        // f32 [64][128] out staging half (aliases MB after LN2)
#define SMEM_BYTES 73728

// ---- workspace layout (byte offsets) ----
#define WSO_BIAS   0         // f32 [8][64][16][4]  packed (h,i,c16,nt)   131072 B
#define WSO_QKVW   131072    // bf16 [48][32][16][8]       393216 B
#define WSO_PROJW  524288    // bf16 [16][32][16][8]       131072 B
#define WSO_FC1W   655360    // bf16 [64][32][16][8]       524288 B
#define WSO_FC2W   1179648   // bf16 [16][128][16][8]      524288 B  (ends 1703936)

__device__ __forceinline__ unsigned short f2bf(float f) {
  union { float f; unsigned u; } v; v.f = f;
  unsigned r = v.u + 0x7FFFu + ((v.u >> 16) & 1u);
  return (unsigned short)(r >> 16);
}
__device__ __forceinline__ float bf2f(unsigned short b) {
  union { unsigned u; float f; } v; v.u = ((unsigned)b) << 16;
  return v.f;
}
__device__ __forceinline__ int swzb(int row, int byteoff) {  // for rows >=128B
  return byteoff ^ ((row & 7) << 4);
}
__device__ __forceinline__ int swz64(int row, int byteoff) { // for 64B rows
  return byteoff ^ ((row & 3) << 4);
}

// ---------------- prep: pack all weights to bf16 MFMA-fragment layout ----------------
__global__ void prep_pack_kernel(const float* __restrict__ qkv_w,
                                 const float* __restrict__ proj_w,
                                 const float* __restrict__ fc1_w,
                                 const float* __restrict__ fc2_w,
                                 unsigned char* __restrict__ wsb) {
  int e = blockIdx.x * 256 + threadIdx.x;   // 0 .. 786431
  const float* src; unsigned short* dst; int K, N; int eo;
  if (e < 196608)       { eo = e;          src = qkv_w;  dst = (unsigned short*)(wsb + WSO_QKVW);  K = 256;  N = 768; }
  else if (e < 262144)  { eo = e - 196608; src = proj_w; dst = (unsigned short*)(wsb + WSO_PROJW); K = 256;  N = 256; }
  else if (e < 524288)  { eo = e - 262144; src = fc1_w;  dst = (unsigned short*)(wsb + WSO_FC1W);  K = 256;  N = 1024; }
  else                  { eo = e - 524288; src = fc2_w;  dst = (unsigned short*)(wsb + WSO_FC2W);  K = 1024; N = 256; }
  int j = eo & 7, c = (eo >> 3) & 15, rest = eo >> 7;
  int Kg = K >> 3;
  int kg = rest % Kg, nt = rest / Kg;
  dst[eo] = f2bf(src[(kg * 8 + j) * N + nt * 16 + c]);
}

// ---------------- prep: relative-position-bias table via CPB MLP (packed float4) ----------------
__global__ void prep_bias_kernel(const float* __restrict__ cpb_w1,
                                 const float* __restrict__ cpb_b1,
                                 const float* __restrict__ cpb_w2,
                                 unsigned char* __restrict__ wsb) {
  __shared__ float bt[225][8];
  int tid = threadIdx.x;
  for (int t = tid; t < 225; t += 256) {
    int a = t / 15, b = t % 15;
    float r0 = (float)(a - 7) * (8.0f / 7.0f);
    float r1 = (float)(b - 7) * (8.0f / 7.0f);
    float f0 = (r0 >= 0.f ? 1.f : -1.f) * log2f(fabsf(r0) + 1.f) * (1.f / 3.f);
    float f1 = (r1 >= 0.f ? 1.f : -1.f) * log2f(fabsf(r1) + 1.f) * (1.f / 3.f);
    float acc[8] = {0.f,0.f,0.f,0.f,0.f,0.f,0.f,0.f};
    for (int k = 0; k < 512; ++k) {
      float hv = f0 * cpb_w1[k] + f1 * cpb_w1[512 + k] + cpb_b1[k];
      hv = fmaxf(hv, 0.f);
      #pragma unroll
      for (int h = 0; h < 8; ++h) acc[h] += hv * cpb_w2[k * 8 + h];
    }
    #pragma unroll
    for (int h = 0; h < 8; ++h) bt[t][h] = acc[h];
  }
  __syncthreads();
  // packed layout: biasP[((h*64+i)*16 + c16)*4 + nt] = 16*sigmoid(rpe[h][i][nt*16+c16])
  float* biasp = (float*)(wsb + WSO_BIAS);
  for (int e = tid; e < 32768; e += 256) {
    int nn = e & 3, cc = (e >> 2) & 15, i = (e >> 6) & 63, h = e >> 12;
    int j = nn * 16 + cc;
    int dr = (i >> 3) - (j >> 3) + 7, dc = (i & 7) - (j & 7) + 7;
    float v = bt[dr * 15 + dc][h];
    biasp[e] = 16.f / (1.f + expf(-v));
  }
}

// ---------------- main fused per-window kernel ----------------
__global__ __launch_bounds__(256, 2)
void swin_block_kernel(const float* __restrict__ x,
                       const float* __restrict__ ls,
                       const float* __restrict__ proj_b,
                       const float* __restrict__ ln1w, const float* __restrict__ ln1b,
                       const float* __restrict__ fc1b,
                       const float* __restrict__ fc2b,
                       const float* __restrict__ ln2w, const float* __restrict__ ln2b,
                       const unsigned char* __restrict__ wsb,
                       float* __restrict__ out) {
  extern __shared__ char sm[];
  const int tid = threadIdx.x;
  const int w = tid >> 6;
  const int lane = tid & 63;
  const int g = lane >> 4;
  const int c16 = lane & 15;

  const int blk = blockIdx.x;
  const int bb = blk >> 10;
  const int widx = blk & 1023;
  const int wi = widx >> 5, wj = widx & 31;

  const f32x4* biasv = (const f32x4*)(wsb + WSO_BIAS);
  const unsigned short* qkvw = (const unsigned short*)(wsb + WSO_QKVW);
  const unsigned short* projw = (const unsigned short*)(wsb + WSO_PROJW);
  const unsigned short* fc1w = (const unsigned short*)(wsb + WSO_FC1W);
  const unsigned short* fc2w = (const unsigned short*)(wsb + WSO_FC2W);

  // ---------- Phase 1: load shifted window -> XW (bf16, swizzled) ----------
  for (int it = 0; it < 16; ++it) {
    int f = tid + it * 256;              // 0..4095 float4 units
    int c = f >> 4;
    int u = f & 15;
    int tr = u >> 1, tc4 = (u & 1) * 4;
    int rp = (wi * 8 + tr + 4) & 255;
    int cp = (wj * 8 + tc4 + 4) & 255;
    const float4 v = *(const float4*)(x + ((((size_t)bb * 256 + c) * 256 + rp) * 256 + cp));
    int t0 = tr * 8 + tc4;
    float vv[4] = {v.x, v.y, v.z, v.w};
    #pragma unroll
    for (int e = 0; e < 4; ++e) {
      int t = t0 + e;
      *(unsigned short*)(sm + L_XW + t * 512 + swzb(t, c * 2)) = f2bf(vv[e]);
    }
  }
  __syncthreads();

  // persistent proj accumulator (built incrementally per head)
  f32x4 accP[4][4];
  #pragma unroll
  for (int a = 0; a < 4; ++a)
    #pragma unroll
    for (int b = 0; b < 4; ++b) accP[a][b] = f32x4{0.f,0.f,0.f,0.f};

  // ---------- attention (+fused proj) per head pair ----------
  #pragma unroll 1
  for (int hp = 0; hp < 4; ++hp) {
    // qkv GEMM for heads 2hp,2hp+1: 12 N-tiles, wave w -> locals w*3..w*3+2
    f32x4 acc[3][4];
    #pragma unroll
    for (int a = 0; a < 3; ++a)
      #pragma unroll
      for (int b = 0; b < 4; ++b) acc[a][b] = f32x4{0.f,0.f,0.f,0.f};
    int gtile[3];
    #pragma unroll
    for (int tl = 0; tl < 3; ++tl) {
      int local = w * 3 + tl;
      int kind = local >> 2, sub = local & 3;
      int hh = sub >> 1, dt = sub & 1;
      gtile[tl] = kind * 16 + (2 * hp + hh) * 2 + dt;
    }
    for (int k0 = 0; k0 < 256; k0 += 32) {
      s16x8 af[4];
      #pragma unroll
      for (int mt = 0; mt < 4; ++mt) {
        int row = mt * 16 + c16;
        af[mt] = *(const s16x8*)(sm + L_XW + row * 512 + swzb(row, (k0 + g * 8) * 2));
      }
      #pragma unroll
      for (int tl = 0; tl < 3; ++tl) {
        s16x8 bfr = *(const s16x8*)(qkvw + ((gtile[tl] * 32 + (k0 >> 3) + g) * 16 + c16) * 8);
        #pragma unroll
        for (int mt = 0; mt < 4; ++mt)
          acc[tl][mt] = __builtin_amdgcn_mfma_f32_16x16x32_bf16(af[mt], bfr, acc[tl][mt], 0, 0, 0);
      }
    }
    // epilogue: q,k -> QK[hh]; v -> VT[hh] transposed
    #pragma unroll
    for (int tl = 0; tl < 3; ++tl) {
      int local = w * 3 + tl;
      int kind = local >> 2, sub = local & 3;
      int hh = sub >> 1, dt = sub & 1;
      #pragma unroll
      for (int mt = 0; mt < 4; ++mt)
        #pragma unroll
        for (int r = 0; r < 4; ++r) {
          int i = mt * 16 + 4 * g + r;
          unsigned short bv = f2bf(acc[tl][mt][r]);
          if (kind == 0) {
            *(unsigned short*)(sm + L_QK + hh * 8192 + i * 128 + swzb(i, (dt * 16 + c16) * 2)) = bv;
          } else if (kind == 1) {
            *(unsigned short*)(sm + L_QK + hh * 8192 + i * 128 + swzb(i, 64 + (dt * 16 + c16) * 2)) = bv;
          } else {
            int d = dt * 16 + c16;
            *(unsigned short*)(sm + L_VT + hh * 4096 + d * 128 + swzb(d, i * 2)) = bv;
          }
        }
    }
    __syncthreads();

    // cosine-normalize q (with logit scale) and k, in place; one thread per (hh,qi,row)
    {
      int hh2 = tid >> 7, qi = (tid >> 6) & 1, t = tid & 63;
      char* base = sm + L_QK + hh2 * 8192 + t * 128;
      float vals[32];
      float ss = 0.f;
      #pragma unroll
      for (int b = 0; b < 4; ++b) {
        s16x8 vb = *(const s16x8*)(base + swzb(t, qi * 64 + b * 16));
        #pragma unroll
        for (int e = 0; e < 8; ++e) { float fv = bf2f((unsigned short)vb[e]); vals[b*8+e] = fv; ss += fv * fv; }
      }
      float scale = 1.f;
      if (qi == 0) scale = __expf(fminf(ls[2 * hp + hh2], 4.6051702f));
      float inv = scale / fmaxf(sqrtf(ss), 1e-12f);
      #pragma unroll
      for (int b = 0; b < 4; ++b) {
        s16x8 vb;
        #pragma unroll
        for (int e = 0; e < 8; ++e) vb[e] = (short)f2bf(vals[b*8+e] * inv);
        *(s16x8*)(base + swzb(t, qi * 64 + b * 16)) = vb;
      }
    }
    __syncthreads();

    #pragma unroll 1
    for (int hh = 0; hh < 2; ++hh) {
      int h = 2 * hp + hh;
      // prefetch packed bias rows (independent of S) — one float4 per r
      f32x4 bb4[4];
      #pragma unroll
      for (int r = 0; r < 4; ++r) {
        int i = 16 * w + 4 * g + r;
        bb4[r] = biasv[(h * 64 + i) * 16 + c16];
      }
      // S = qn @ kn^T  (K = HD = 32 -> single MFMA per col tile)
      int arow = 16 * w + c16;
      s16x8 aq = *(const s16x8*)(sm + L_QK + hh * 8192 + arow * 128 + swzb(arow, g * 16));
      f32x4 s[4];
      #pragma unroll
      for (int nt = 0; nt < 4; ++nt) {
        int brow = nt * 16 + c16;
        s16x8 bk = *(const s16x8*)(sm + L_QK + hh * 8192 + brow * 128 + swzb(brow, 64 + g * 16));
        s[nt] = __builtin_amdgcn_mfma_f32_16x16x32_bf16(aq, bk, f32x4{0.f,0.f,0.f,0.f}, 0, 0, 0);
      }
      // shift-mask labels (edge windows only)
      int labi[4], labj[4];
      #pragma unroll
      for (int r = 0; r < 4; ++r) {
        int i = 16 * w + 4 * g + r;
        int tr = i >> 3, tc = i & 7;
        labi[r] = ((wi == 31) ? (tr >= 4 ? 2 : 1) : 0) * 3 + ((wj == 31) ? (tc >= 4 ? 2 : 1) : 0);
      }
      #pragma unroll
      for (int nt = 0; nt < 4; ++nt) {
        int j = nt * 16 + c16;
        int tr = j >> 3, tc = j & 7;
        labj[nt] = ((wi == 31) ? (tr >= 4 ? 2 : 1) : 0) * 3 + ((wj == 31) ? (tc >= 4 ? 2 : 1) : 0);
      }
      float p[4][4];
      #pragma unroll
      for (int r = 0; r < 4; ++r) {
        float mx = -1e30f;
        float vv[4];
        #pragma unroll
        for (int nt = 0; nt < 4; ++nt) {
          float v = s[nt][r] + bb4[r][nt];
          if (labi[r] != labj[nt]) v -= 100.f;
          vv[nt] = v;
          mx = fmaxf(mx, v);
        }
        mx = fmaxf(mx, __shfl_xor(mx, 1));
        mx = fmaxf(mx, __shfl_xor(mx, 2));
        mx = fmaxf(mx, __shfl_xor(mx, 4));
        mx = fmaxf(mx, __shfl_xor(mx, 8));
        float sum = 0.f;
        #pragma unroll
        for (int nt = 0; nt < 4; ++nt) { vv[nt] = __expf(vv[nt] - mx); sum += vv[nt]; }
        sum += __shfl_xor(sum, 1);
        sum += __shfl_xor(sum, 2);
        sum += __shfl_xor(sum, 4);
        sum += __shfl_xor(sum, 8);
        float inv = 1.f / sum;
        #pragma unroll
        for (int nt = 0; nt < 4; ++nt) p[nt][r] = vv[nt] * inv;
      }
      #pragma unroll
      for (int nt = 0; nt < 4; ++nt)
        #pragma unroll
        for (int r = 0; r < 4; ++r) {
          int i = 16 * w + 4 * g + r;
          int j = nt * 16 + c16;
          *(unsigned short*)(sm + L_P + i * 128 + swzb(i, j * 2)) = f2bf(p[nt][r]);
        }
      __syncthreads();   // B1: P complete

      // O_head = P @ V  (rows 16w.., 2 d-tiles, K=64)
      f32x4 oacc[2] = {f32x4{0.f,0.f,0.f,0.f}, f32x4{0.f,0.f,0.f,0.f}};
      #pragma unroll
      for (int k0 = 0; k0 < 64; k0 += 32) {
        int prow = 16 * w + c16;
        s16x8 pa = *(const s16x8*)(sm + L_P + prow * 128 + swzb(prow, (k0 + g * 8) * 2));
        #pragma unroll
        for (int nt = 0; nt < 2; ++nt) {
          int vrow = nt * 16 + c16;
          s16x8 vb = *(const s16x8*)(sm + L_VT + hh * 4096 + vrow * 128 + swzb(vrow, (k0 + g * 8) * 2));
          oacc[nt] = __builtin_amdgcn_mfma_f32_16x16x32_bf16(pa, vb, oacc[nt], 0, 0, 0);
        }
      }
      // stage O slice for this head
      #pragma unroll
      for (int nt = 0; nt < 2; ++nt)
        #pragma unroll
        for (int r = 0; r < 4; ++r) {
          int i = 16 * w + 4 * g + r;
          int d = nt * 16 + c16;
          *(unsigned short*)(sm + L_OS + hh * 4096 + i * 64 + swz64(i, d * 2)) = f2bf(oacc[nt][r]);
        }
      __syncthreads();   // B2: O slice complete

      // fused proj partial: accP += O_slice @ projw[h*32 .. h*32+31, :]   (K=32, one step)
      s16x8 paf[4];
      #pragma unroll
      for (int mt = 0; mt < 4; ++mt) {
        int row = mt * 16 + c16;
        paf[mt] = *(const s16x8*)(sm + L_OS + hh * 4096 + row * 64 + swz64(row, g * 16));
      }
      #pragma unroll
      for (int nt = 0; nt < 4; ++nt) {
        s16x8 bfr = *(const s16x8*)(projw + (((w * 4 + nt) * 32 + h * 4 + g) * 16 + c16) * 8);
        #pragma unroll
        for (int mt = 0; mt < 4; ++mt)
          accP[nt][mt] = __builtin_amdgcn_mfma_f32_16x16x32_bf16(paf[mt], bfr, accP[nt][mt], 0, 0, 0);
      }
    }
  }

  // ---------- proj epilogue: o + proj_b -> Y (bf16, over QK/VT/P region) ----------
  #pragma unroll
  for (int nt = 0; nt < 4; ++nt) {
    int col = w * 64 + nt * 16 + c16;
    float pb = proj_b[col];
    #pragma unroll
    for (int mt = 0; mt < 4; ++mt)
      #pragma unroll
      for (int r = 0; r < 4; ++r) {
        int i = mt * 16 + 4 * g + r;
        *(unsigned short*)(sm + L_Y + i * 512 + swzb(i, col * 2)) = f2bf(accP[nt][mt][r] + pb);
      }
  }
  __syncthreads();

  // ---------- LN1 + residual: y = LN(o)*g+b + xw, in place on Y (bf16) ----------
  {
    int t = tid >> 2, q4 = tid & 3;
    float v[64];
    float s1 = 0.f;
    #pragma unroll
    for (int b2 = 0; b2 < 8; ++b2) {
      s16x8 vb = *(const s16x8*)(sm + L_Y + t * 512 + swzb(t, q4 * 128 + b2 * 16));
      #pragma unroll
      for (int e = 0; e < 8; ++e) { float fv = bf2f((unsigned short)vb[e]); v[b2*8+e] = fv; s1 += fv; }
    }
    s1 += __shfl_xor(s1, 1);
    s1 += __shfl_xor(s1, 2);
    float mu = s1 * (1.f / 256.f);
    float s2 = 0.f;
    #pragma unroll
    for (int e = 0; e < 64; ++e) { float d = v[e] - mu; s2 += d * d; }
    s2 += __shfl_xor(s2, 1);
    s2 += __shfl_xor(s2, 2);
    float rs = rsqrtf(s2 * (1.f / 256.f) + 1e-5f);
    #pragma unroll
    for (int e = 0; e < 64; ++e) {
      int c = q4 * 64 + e;
      float xwv = bf2f(*(const unsigned short*)(sm + L_XW + t * 512 + swzb(t, c * 2)));
      float yv = (v[e] - mu) * rs * ln1w[c] + ln1b[c] + xwv;
      *(unsigned short*)(sm + L_Y + t * 512 + swzb(t, c * 2)) = f2bf(yv);
    }
  }
  __syncthreads();

  // ---------- MLP: fc1(gelu) in 4 chunks, fc2 accumulated in registers ----------
  f32x4 acc2[4][4];
  #pragma unroll
  for (int a = 0; a < 4; ++a)
    #pragma unroll
    for (int b = 0; b < 4; ++b) acc2[a][b] = f32x4{0.f,0.f,0.f,0.f};

  #pragma unroll 1
  for (int cc = 0; cc < 4; ++cc) {
    f32x4 acc1[4][4];
    #pragma unroll
    for (int a = 0; a < 4; ++a)
      #pragma unroll
      for (int b = 0; b < 4; ++b) acc1[a][b] = f32x4{0.f,0.f,0.f,0.f};
    for (int k0 = 0; k0 < 256; k0 += 32) {
      s16x8 af[4];
      #pragma unroll
      for (int mt = 0; mt < 4; ++mt) {
        int row = mt * 16 + c16;
        af[mt] = *(const s16x8*)(sm + L_Y + row * 512 + swzb(row, (k0 + g * 8) * 2));
      }
      #pragma unroll
      for (int nt = 0; nt < 4; ++nt) {
        int gt = cc * 16 + w * 4 + nt;
        s16x8 bfr = *(const s16x8*)(fc1w + ((gt * 32 + (k0 >> 3) + g) * 16 + c16) * 8);
        #pragma unroll
        for (int mt = 0; mt < 4; ++mt)
          acc1[nt][mt] = __builtin_amdgcn_mfma_f32_16x16x32_bf16(af[mt], bfr, acc1[nt][mt], 0, 0, 0);
      }
    }
    // gelu (tanh form, exact-vs-approx <=1e-3) + store H chunk (aliases XW; dead after LN1)
    #pragma unroll
    for (int nt = 0; nt < 4; ++nt) {
      int coll = w * 64 + nt * 16 + c16;
      float b1v = fc1b[cc * 256 + coll];
      #pragma unroll
      for (int mt = 0; mt < 4; ++mt)
        #pragma unroll
        for (int r = 0; r < 4; ++r) {
          int i = mt * 16 + 4 * g + r;
          float u = acc1[nt][mt][r] + b1v;
          float z = 0.7978845608f * u * (1.f + 0.044715f * u * u);
          float e2 = __expf(2.f * z);
          float ge = u * e2 / (e2 + 1.f);
          *(unsigned short*)(sm + L_H + i * 512 + swzb(i, coll * 2)) = f2bf(ge);
        }
    }
    __syncthreads();
    // fc2 partial: acc2 += H_chunk @ fc2[cc*256.., :]
    for (int k0 = 0; k0 < 256; k0 += 32) {
      s16x8 af[4];
      #pragma unroll
      for (int mt = 0; mt < 4; ++mt) {
        int row = mt * 16 + c16;
        af[mt] = *(const s16x8*)(sm + L_H + row * 512 + swzb(row, (k0 + g * 8) * 2));
      }
      #pragma unroll
      for (int nt = 0; nt < 4; ++nt) {
        int kg = cc * 32 + (k0 >> 3) + g;
        s16x8 bfr = *(const s16x8*)(fc2w + (((w * 4 + nt) * 128 + kg) * 16 + c16) * 8);
        #pragma unroll
        for (int mt = 0; mt < 4; ++mt)
          acc2[nt][mt] = __builtin_amdgcn_mfma_f32_16x16x32_bf16(af[mt], bfr, acc2[nt][mt], 0, 0, 0);
      }
    }
    __syncthreads();
  }

  // ---------- fc2 epilogue -> MB bf16 (aliases H) ----------
  #pragma unroll
  for (int nt = 0; nt < 4; ++nt) {
    int col = w * 64 + nt * 16 + c16;
    float b2v = fc2b[col];
    #pragma unroll
    for (int mt = 0; mt < 4; ++mt)
      #pragma unroll
      for (int r = 0; r < 4; ++r) {
        int i = mt * 16 + 4 * g + r;
        *(unsigned short*)(sm + L_MB + i * 512 + swzb(i, col * 2)) = f2bf(acc2[nt][mt][r] + b2v);
      }
  }
  __syncthreads();

  // ---------- LN2 + residual in registers ----------
  int t2 = tid >> 2, q4 = tid & 3;
  float v[64];
  {
    float s1 = 0.f;
    #pragma unroll
    for (int b2 = 0; b2 < 8; ++b2) {
      s16x8 vb = *(const s16x8*)(sm + L_MB + t2 * 512 + swzb(t2, q4 * 128 + b2 * 16));
      #pragma unroll
      for (int e = 0; e < 8; ++e) { float fv = bf2f((unsigned short)vb[e]); v[b2*8+e] = fv; s1 += fv; }
    }
    s1 += __shfl_xor(s1, 1);
    s1 += __shfl_xor(s1, 2);
    float mu = s1 * (1.f / 256.f);
    float s2 = 0.f;
    #pragma unroll
    for (int e = 0; e < 64; ++e) { float d = v[e] - mu; s2 += d * d; }
    s2 += __shfl_xor(s2, 1);
    s2 += __shfl_xor(s2, 2);
    float rs = rsqrtf(s2 * (1.f / 256.f) + 1e-5f);
    #pragma unroll
    for (int e = 0; e < 64; ++e) {
      int c = q4 * 64 + e;
      float yres = bf2f(*(const unsigned short*)(sm + L_Y + t2 * 512 + swzb(t2, c * 2)));
      v[e] = (v[e] - mu) * rs * ln2w[c] + ln2b[c] + yres;
    }
  }
  __syncthreads();   // all MB reads done before stage (same region) is written

  // ---------- output: f32 staging half-by-half + window reverse + un-shift ----------
  #pragma unroll 1
  for (int hf = 0; hf < 2; ++hf) {
    if ((q4 >> 1) == hf) {
      #pragma unroll
      for (int e = 0; e < 64; ++e) {
        int cl = (q4 & 1) * 64 + e;
        *(float*)(sm + L_ST + t2 * 512 + swzb(t2, cl * 4)) = v[e];
      }
    }
    __syncthreads();
    for (int it = 0; it < 8; ++it) {
      int f = tid + it * 256;           // 0..2047 float4 units
      int cl = f >> 4;                  // 0..127
      int u = f & 15;
      int tr = u >> 1, tc4 = (u & 1) * 4;
      float tmp[4];
      #pragma unroll
      for (int e = 0; e < 4; ++e) {
        int tok = tr * 8 + tc4 + e;
        tmp[e] = *(const float*)(sm + L_ST + tok * 512 + swzb(tok, cl * 4));
      }
      float4 vv; vv.x = tmp[0]; vv.y = tmp[1]; vv.z = tmp[2]; vv.w = tmp[3];
      int c = hf * 128 + cl;
      int rp = (wi * 8 + tr + 4) & 255;
      int cp = (wj * 8 + tc4 + 4) & 255;
      *(float4*)(out + ((((size_t)bb * 256 + c) * 256 + rp) * 256 + cp)) = vv;
    }
    __syncthreads();
  }
}

extern "C" void kernel_launch(void* const* d_in, const int* in_sizes, int n_in,
                              void* d_out, int out_size, void* d_ws, size_t ws_size,
                              hipStream_t stream) {
  const float* x      = (const float*)d_in[0];
  const float* qkv_w  = (const float*)d_in[1];
  const float* ls     = (const float*)d_in[2];
  const float* proj_w = (const float*)d_in[3];
  const float* proj_b = (const float*)d_in[4];
  const float* ln1w   = (const float*)d_in[5];
  const float* ln1b   = (const float*)d_in[6];
  const float* fc1_w  = (const float*)d_in[7];
  const float* fc1b   = (const float*)d_in[8];
  const float* fc2_w  = (const float*)d_in[9];
  const float* fc2b   = (const float*)d_in[10];
  const float* ln2w   = (const float*)d_in[11];
  const float* ln2b   = (const float*)d_in[12];
  const float* cpb_w1 = (const float*)d_in[13];
  const float* cpb_b1 = (const float*)d_in[14];
  const float* cpb_w2 = (const float*)d_in[15];
  unsigned char* wsb = (unsigned char*)d_ws;
  float* out = (float*)d_out;

  hipFuncSetAttribute(reinterpret_cast<const void*>(swin_block_kernel),
                      hipFuncAttributeMaxDynamicSharedMemorySize, SMEM_BYTES);

  prep_pack_kernel<<<3072, 256, 0, stream>>>(qkv_w, proj_w, fc1_w, fc2_w, wsb);
  prep_bias_kernel<<<1, 256, 0, stream>>>(cpb_w1, cpb_b1, cpb_w2, wsb);
  swin_block_kernel<<<2048, 256, SMEM_BYTES, stream>>>(
      x, ls, proj_b, ln1w, ln1b, fc1b, fc2b, ln2w, ln2b, wsb, out);
}

// Round 3
// 1375.087 us; speedup vs baseline: 1.0994x; 1.0994x over previous
//
#include <hip/hip_runtime.h>

typedef __attribute__((ext_vector_type(4))) float f32x4;
typedef __attribute__((ext_vector_type(8))) short s16x8;

// ---- LDS layout (byte offsets), total 73728 B -> 2 blocks/CU ----
#define L_XW   0        // bf16 [64][256] swz, stride 512B  (later: H chunk, mlp bf16)
#define L_QK   32768    // bf16 [2][64][64] (q cols 0-31 | k cols 32-63), stride 128B/row
#define L_VT   49152    // bf16 [2][32][64] v transposed, stride 128B
#define L_P    57344    // bf16 [64][64], stride 128B
#define L_OS   65536    // bf16 [2][64][32] per-head O slice, stride 64B
#define L_Y    32768    // bf16 [64][256] swz, stride 512B (aliases QK/VT/P after attention)
#define L_H    0        // bf16 [64][256] (aliases XW after LN1)
#define L_MB   0        // bf16 [64][256] mlp pre-LN (aliases H after fc2)
#define SMEM_BYTES 73728

// ---- workspace layout (byte offsets) ----
#define WSO_BIAS   0          // f32 [8][64][16][4] packed (h,i,c16,nt)   131072 B
#define WSO_QKVW   131072     // bf16 [48][32][16][8]       393216 B
#define WSO_PROJW  524288     // bf16 [16][32][16][8]       131072 B
#define WSO_FC1W   655360     // bf16 [64][32][16][8]       524288 B
#define WSO_FC2W   1179648    // bf16 [16][128][16][8]      524288 B
#define WSO_SIN    1703936ULL // bf16 [2][65536][256]       67108864 B
#define WSO_SOUT   68812800ULL// bf16 [2][65536][256]       67108864 B  (ends ~136 MB)

__device__ __forceinline__ unsigned short f2bf(float f) {
  union { float f; unsigned u; } v; v.f = f;
  unsigned r = v.u + 0x7FFFu + ((v.u >> 16) & 1u);
  return (unsigned short)(r >> 16);
}
__device__ __forceinline__ float bf2f(unsigned short b) {
  union { unsigned u; float f; } v; v.u = ((unsigned)b) << 16;
  return v.f;
}
__device__ __forceinline__ int swzb(int row, int byteoff) {  // for rows >=128B
  return byteoff ^ ((row & 7) << 4);
}
__device__ __forceinline__ int swz64(int row, int byteoff) { // for 64B rows
  return byteoff ^ ((row & 3) << 4);
}

// ---------------- prep: pack all weights to bf16 MFMA-fragment layout ----------------
__global__ void prep_pack_kernel(const float* __restrict__ qkv_w,
                                 const float* __restrict__ proj_w,
                                 const float* __restrict__ fc1_w,
                                 const float* __restrict__ fc2_w,
                                 unsigned char* __restrict__ wsb) {
  int e = blockIdx.x * 256 + threadIdx.x;   // 0 .. 786431
  const float* src; unsigned short* dst; int K, N; int eo;
  if (e < 196608)       { eo = e;          src = qkv_w;  dst = (unsigned short*)(wsb + WSO_QKVW);  K = 256;  N = 768; }
  else if (e < 262144)  { eo = e - 196608; src = proj_w; dst = (unsigned short*)(wsb + WSO_PROJW); K = 256;  N = 256; }
  else if (e < 524288)  { eo = e - 262144; src = fc1_w;  dst = (unsigned short*)(wsb + WSO_FC1W);  K = 256;  N = 1024; }
  else                  { eo = e - 524288; src = fc2_w;  dst = (unsigned short*)(wsb + WSO_FC2W);  K = 1024; N = 256; }
  int j = eo & 7, c = (eo >> 3) & 15, rest = eo >> 7;
  int Kg = K >> 3;
  int kg = rest % Kg, nt = rest / Kg;
  dst[eo] = f2bf(src[(kg * 8 + j) * N + nt * 16 + c]);
}

// ---------------- prep: relative-position-bias table via CPB MLP (packed float4) ----------------
__global__ void prep_bias_kernel(const float* __restrict__ cpb_w1,
                                 const float* __restrict__ cpb_b1,
                                 const float* __restrict__ cpb_w2,
                                 unsigned char* __restrict__ wsb) {
  __shared__ float bt[225][8];
  int tid = threadIdx.x;
  for (int t = tid; t < 225; t += 256) {
    int a = t / 15, b = t % 15;
    float r0 = (float)(a - 7) * (8.0f / 7.0f);
    float r1 = (float)(b - 7) * (8.0f / 7.0f);
    float f0 = (r0 >= 0.f ? 1.f : -1.f) * log2f(fabsf(r0) + 1.f) * (1.f / 3.f);
    float f1 = (r1 >= 0.f ? 1.f : -1.f) * log2f(fabsf(r1) + 1.f) * (1.f / 3.f);
    float acc[8] = {0.f,0.f,0.f,0.f,0.f,0.f,0.f,0.f};
    for (int k = 0; k < 512; ++k) {
      float hv = f0 * cpb_w1[k] + f1 * cpb_w1[512 + k] + cpb_b1[k];
      hv = fmaxf(hv, 0.f);
      #pragma unroll
      for (int h = 0; h < 8; ++h) acc[h] += hv * cpb_w2[k * 8 + h];
    }
    #pragma unroll
    for (int h = 0; h < 8; ++h) bt[t][h] = acc[h];
  }
  __syncthreads();
  float* biasp = (float*)(wsb + WSO_BIAS);
  for (int e = tid; e < 32768; e += 256) {
    int nn = e & 3, cc = (e >> 2) & 15, i = (e >> 6) & 63, h = e >> 12;
    int j = nn * 16 + cc;
    int dr = (i >> 3) - (j >> 3) + 7, dc = (i & 7) - (j & 7) + 7;
    float v = bt[dr * 15 + dc][h];
    biasp[e] = 16.f / (1.f + expf(-v));
  }
}

// ---------------- pass A: x[b][c][p] f32 -> sin[b][p][c] bf16 (tiled transpose) ----------------
__global__ __launch_bounds__(256)
void transpose_in_kernel(const float* __restrict__ x, unsigned char* __restrict__ wsb) {
  __shared__ float tile[64][65];
  int pb = blockIdx.x & 1023;
  int cg = (blockIdx.x >> 10) & 3;
  int b  = blockIdx.x >> 12;
  int p0 = pb * 64, c0 = cg * 64;
  int tid = threadIdx.x;
  unsigned short* sg = (unsigned short*)(wsb + WSO_SIN);

  int pi = tid & 63, cq = tid >> 6;       // read: 4 c-rows per iter, coalesced along p
  for (int r = 0; r < 16; ++r) {
    int c = cq * 16 + r;
    tile[pi][c] = x[((size_t)(b * 256 + c0 + c)) * 65536 + p0 + pi];
  }
  __syncthreads();
  int po = tid >> 2, co = tid & 3;        // write: 32B per thread, coalesced along c
  s16x8 pk0, pk1;
  #pragma unroll
  for (int j = 0; j < 8; ++j) {
    pk0[j] = (short)f2bf(tile[po][co * 16 + j]);
    pk1[j] = (short)f2bf(tile[po][co * 16 + 8 + j]);
  }
  unsigned short* dp = sg + ((size_t)b * 65536 + p0 + po) * 256 + c0 + co * 16;
  *(s16x8*)(dp) = pk0;
  *(s16x8*)(dp + 8) = pk1;
}

// ---------------- pass B: sout[b][p][c] bf16 -> out[b][c][p] f32 (tiled transpose) ----------------
__global__ __launch_bounds__(256)
void transpose_out_kernel(const unsigned char* __restrict__ wsb, float* __restrict__ out) {
  __shared__ float tile[64][65];
  int pb = blockIdx.x & 1023;
  int cg = (blockIdx.x >> 10) & 3;
  int b  = blockIdx.x >> 12;
  int p0 = pb * 64, c0 = cg * 64;
  int tid = threadIdx.x;
  const unsigned short* sg = (const unsigned short*)(wsb + WSO_SOUT);

  int pi = tid >> 2, cq = tid & 3;        // read: 32B per thread, coalesced along c
  const unsigned short* rp = sg + ((size_t)b * 65536 + p0 + pi) * 256 + c0 + cq * 16;
  s16x8 a0 = *(const s16x8*)(rp);
  s16x8 a1 = *(const s16x8*)(rp + 8);
  #pragma unroll
  for (int j = 0; j < 8; ++j) {
    tile[pi][cq * 16 + j]     = bf2f((unsigned short)a0[j]);
    tile[pi][cq * 16 + 8 + j] = bf2f((unsigned short)a1[j]);
  }
  __syncthreads();
  int ci = tid >> 6, pi2 = tid & 63;      // write: coalesced along p
  for (int r = 0; r < 16; ++r) {
    int c = ci * 16 + r;
    out[((size_t)(b * 256 + c0 + c)) * 65536 + p0 + pi2] = tile[pi2][c];
  }
}

// ---------------- main fused per-window kernel ----------------
__global__ __launch_bounds__(256, 2)
void swin_block_kernel(const float* __restrict__ ls,
                       const float* __restrict__ proj_b,
                       const float* __restrict__ ln1w, const float* __restrict__ ln1b,
                       const float* __restrict__ fc1b,
                       const float* __restrict__ fc2b,
                       const float* __restrict__ ln2w, const float* __restrict__ ln2b,
                       unsigned char* __restrict__ wsb) {
  extern __shared__ char sm[];
  const int tid = threadIdx.x;
  const int w = tid >> 6;
  const int lane = tid & 63;
  const int g = lane >> 4;
  const int c16 = lane & 15;

  const int blk = blockIdx.x;
  const int bb = blk >> 10;
  const int widx = blk & 1023;
  const int wi = widx >> 5, wj = widx & 31;

  const f32x4* biasv = (const f32x4*)(wsb + WSO_BIAS);
  const unsigned short* qkvw = (const unsigned short*)(wsb + WSO_QKVW);
  const unsigned short* projw = (const unsigned short*)(wsb + WSO_PROJW);
  const unsigned short* fc1w = (const unsigned short*)(wsb + WSO_FC1W);
  const unsigned short* fc2w = (const unsigned short*)(wsb + WSO_FC2W);
  const unsigned short* sin_ = (const unsigned short*)(wsb + WSO_SIN);
  unsigned short* sout = (unsigned short*)(wsb + WSO_SOUT);

  // ---------- Phase 1: copy window from sin (channel-contiguous) -> XW bf16 swz ----------
  #pragma unroll
  for (int it = 0; it < 8; ++it) {
    int u = tid + it * 256;              // 16B units: u = t*32 + cu
    int t = u >> 5, cu = u & 31;
    int rp = (wi * 8 + (t >> 3) + 4) & 255;
    int cp = (wj * 8 + (t & 7) + 4) & 255;
    size_t pix = (size_t)bb * 65536 + rp * 256 + cp;
    s16x8 v = *(const s16x8*)(sin_ + pix * 256 + cu * 8);
    *(s16x8*)(sm + L_XW + t * 512 + swzb(t, cu * 16)) = v;
  }
  __syncthreads();

  // persistent proj accumulator (built incrementally per head)
  f32x4 accP[4][4];
  #pragma unroll
  for (int a = 0; a < 4; ++a)
    #pragma unroll
    for (int b = 0; b < 4; ++b) accP[a][b] = f32x4{0.f,0.f,0.f,0.f};

  // ---------- attention (+fused proj) per head pair ----------
  #pragma unroll 1
  for (int hp = 0; hp < 4; ++hp) {
    f32x4 acc[3][4];
    #pragma unroll
    for (int a = 0; a < 3; ++a)
      #pragma unroll
      for (int b = 0; b < 4; ++b) acc[a][b] = f32x4{0.f,0.f,0.f,0.f};
    int gtile[3];
    #pragma unroll
    for (int tl = 0; tl < 3; ++tl) {
      int local = w * 3 + tl;
      int kind = local >> 2, sub = local & 3;
      int hh = sub >> 1, dt = sub & 1;
      gtile[tl] = kind * 16 + (2 * hp + hh) * 2 + dt;
    }
    for (int k0 = 0; k0 < 256; k0 += 32) {
      s16x8 af[4];
      #pragma unroll
      for (int mt = 0; mt < 4; ++mt) {
        int row = mt * 16 + c16;
        af[mt] = *(const s16x8*)(sm + L_XW + row * 512 + swzb(row, (k0 + g * 8) * 2));
      }
      #pragma unroll
      for (int tl = 0; tl < 3; ++tl) {
        s16x8 bfr = *(const s16x8*)(qkvw + ((gtile[tl] * 32 + (k0 >> 3) + g) * 16 + c16) * 8);
        #pragma unroll
        for (int mt = 0; mt < 4; ++mt)
          acc[tl][mt] = __builtin_amdgcn_mfma_f32_16x16x32_bf16(af[mt], bfr, acc[tl][mt], 0, 0, 0);
      }
    }
    // epilogue: q,k -> QK[hh]; v -> VT[hh] transposed
    #pragma unroll
    for (int tl = 0; tl < 3; ++tl) {
      int local = w * 3 + tl;
      int kind = local >> 2, sub = local & 3;
      int hh = sub >> 1, dt = sub & 1;
      #pragma unroll
      for (int mt = 0; mt < 4; ++mt)
        #pragma unroll
        for (int r = 0; r < 4; ++r) {
          int i = mt * 16 + 4 * g + r;
          unsigned short bv = f2bf(acc[tl][mt][r]);
          if (kind == 0) {
            *(unsigned short*)(sm + L_QK + hh * 8192 + i * 128 + swzb(i, (dt * 16 + c16) * 2)) = bv;
          } else if (kind == 1) {
            *(unsigned short*)(sm + L_QK + hh * 8192 + i * 128 + swzb(i, 64 + (dt * 16 + c16) * 2)) = bv;
          } else {
            int d = dt * 16 + c16;
            *(unsigned short*)(sm + L_VT + hh * 4096 + d * 128 + swzb(d, i * 2)) = bv;
          }
        }
    }
    __syncthreads();

    // cosine-normalize q (with logit scale) and k, in place
    {
      int hh2 = tid >> 7, qi = (tid >> 6) & 1, t = tid & 63;
      char* base = sm + L_QK + hh2 * 8192 + t * 128;
      float vals[32];
      float ss = 0.f;
      #pragma unroll
      for (int b = 0; b < 4; ++b) {
        s16x8 vb = *(const s16x8*)(base + swzb(t, qi * 64 + b * 16));
        #pragma unroll
        for (int e = 0; e < 8; ++e) { float fv = bf2f((unsigned short)vb[e]); vals[b*8+e] = fv; ss += fv * fv; }
      }
      float scale = 1.f;
      if (qi == 0) scale = __expf(fminf(ls[2 * hp + hh2], 4.6051702f));
      float inv = scale / fmaxf(sqrtf(ss), 1e-12f);
      #pragma unroll
      for (int b = 0; b < 4; ++b) {
        s16x8 vb;
        #pragma unroll
        for (int e = 0; e < 8; ++e) vb[e] = (short)f2bf(vals[b*8+e] * inv);
        *(s16x8*)(base + swzb(t, qi * 64 + b * 16)) = vb;
      }
    }
    __syncthreads();

    #pragma unroll 1
    for (int hh = 0; hh < 2; ++hh) {
      int h = 2 * hp + hh;
      f32x4 bb4[4];
      #pragma unroll
      for (int r = 0; r < 4; ++r) {
        int i = 16 * w + 4 * g + r;
        bb4[r] = biasv[(h * 64 + i) * 16 + c16];
      }
      int arow = 16 * w + c16;
      s16x8 aq = *(const s16x8*)(sm + L_QK + hh * 8192 + arow * 128 + swzb(arow, g * 16));
      f32x4 s[4];
      #pragma unroll
      for (int nt = 0; nt < 4; ++nt) {
        int brow = nt * 16 + c16;
        s16x8 bk = *(const s16x8*)(sm + L_QK + hh * 8192 + brow * 128 + swzb(brow, 64 + g * 16));
        s[nt] = __builtin_amdgcn_mfma_f32_16x16x32_bf16(aq, bk, f32x4{0.f,0.f,0.f,0.f}, 0, 0, 0);
      }
      int labi[4], labj[4];
      #pragma unroll
      for (int r = 0; r < 4; ++r) {
        int i = 16 * w + 4 * g + r;
        int tr = i >> 3, tc = i & 7;
        labi[r] = ((wi == 31) ? (tr >= 4 ? 2 : 1) : 0) * 3 + ((wj == 31) ? (tc >= 4 ? 2 : 1) : 0);
      }
      #pragma unroll
      for (int nt = 0; nt < 4; ++nt) {
        int j = nt * 16 + c16;
        int tr = j >> 3, tc = j & 7;
        labj[nt] = ((wi == 31) ? (tr >= 4 ? 2 : 1) : 0) * 3 + ((wj == 31) ? (tc >= 4 ? 2 : 1) : 0);
      }
      float p[4][4];
      #pragma unroll
      for (int r = 0; r < 4; ++r) {
        float mx = -1e30f;
        float vv[4];
        #pragma unroll
        for (int nt = 0; nt < 4; ++nt) {
          float v = s[nt][r] + bb4[r][nt];
          if (labi[r] != labj[nt]) v -= 100.f;
          vv[nt] = v;
          mx = fmaxf(mx, v);
        }
        mx = fmaxf(mx, __shfl_xor(mx, 1));
        mx = fmaxf(mx, __shfl_xor(mx, 2));
        mx = fmaxf(mx, __shfl_xor(mx, 4));
        mx = fmaxf(mx, __shfl_xor(mx, 8));
        float sum = 0.f;
        #pragma unroll
        for (int nt = 0; nt < 4; ++nt) { vv[nt] = __expf(vv[nt] - mx); sum += vv[nt]; }
        sum += __shfl_xor(sum, 1);
        sum += __shfl_xor(sum, 2);
        sum += __shfl_xor(sum, 4);
        sum += __shfl_xor(sum, 8);
        float inv = 1.f / sum;
        #pragma unroll
        for (int nt = 0; nt < 4; ++nt) p[nt][r] = vv[nt] * inv;
      }
      #pragma unroll
      for (int nt = 0; nt < 4; ++nt)
        #pragma unroll
        for (int r = 0; r < 4; ++r) {
          int i = 16 * w + 4 * g + r;
          int j = nt * 16 + c16;
          *(unsigned short*)(sm + L_P + i * 128 + swzb(i, j * 2)) = f2bf(p[nt][r]);
        }
      __syncthreads();   // B1: P complete

      f32x4 oacc[2] = {f32x4{0.f,0.f,0.f,0.f}, f32x4{0.f,0.f,0.f,0.f}};
      #pragma unroll
      for (int k0 = 0; k0 < 64; k0 += 32) {
        int prow = 16 * w + c16;
        s16x8 pa = *(const s16x8*)(sm + L_P + prow * 128 + swzb(prow, (k0 + g * 8) * 2));
        #pragma unroll
        for (int nt = 0; nt < 2; ++nt) {
          int vrow = nt * 16 + c16;
          s16x8 vb = *(const s16x8*)(sm + L_VT + hh * 4096 + vrow * 128 + swzb(vrow, (k0 + g * 8) * 2));
          oacc[nt] = __builtin_amdgcn_mfma_f32_16x16x32_bf16(pa, vb, oacc[nt], 0, 0, 0);
        }
      }
      #pragma unroll
      for (int nt = 0; nt < 2; ++nt)
        #pragma unroll
        for (int r = 0; r < 4; ++r) {
          int i = 16 * w + 4 * g + r;
          int d = nt * 16 + c16;
          *(unsigned short*)(sm + L_OS + hh * 4096 + i * 64 + swz64(i, d * 2)) = f2bf(oacc[nt][r]);
        }
      __syncthreads();   // B2: O slice complete

      s16x8 paf[4];
      #pragma unroll
      for (int mt = 0; mt < 4; ++mt) {
        int row = mt * 16 + c16;
        paf[mt] = *(const s16x8*)(sm + L_OS + hh * 4096 + row * 64 + swz64(row, g * 16));
      }
      #pragma unroll
      for (int nt = 0; nt < 4; ++nt) {
        s16x8 bfr = *(const s16x8*)(projw + (((w * 4 + nt) * 32 + h * 4 + g) * 16 + c16) * 8);
        #pragma unroll
        for (int mt = 0; mt < 4; ++mt)
          accP[nt][mt] = __builtin_amdgcn_mfma_f32_16x16x32_bf16(paf[mt], bfr, accP[nt][mt], 0, 0, 0);
      }
    }
  }

  // ---------- proj epilogue: o + proj_b -> Y (bf16, over QK/VT/P region) ----------
  #pragma unroll
  for (int nt = 0; nt < 4; ++nt) {
    int col = w * 64 + nt * 16 + c16;
    float pb = proj_b[col];
    #pragma unroll
    for (int mt = 0; mt < 4; ++mt)
      #pragma unroll
      for (int r = 0; r < 4; ++r) {
        int i = mt * 16 + 4 * g + r;
        *(unsigned short*)(sm + L_Y + i * 512 + swzb(i, col * 2)) = f2bf(accP[nt][mt][r] + pb);
      }
  }
  __syncthreads();

  // ---------- LN1 + residual: y = LN(o)*g+b + xw, in place on Y (bf16) ----------
  {
    int t = tid >> 2, q4 = tid & 3;
    float v[64];
    float s1 = 0.f;
    #pragma unroll
    for (int b2 = 0; b2 < 8; ++b2) {
      s16x8 vb = *(const s16x8*)(sm + L_Y + t * 512 + swzb(t, q4 * 128 + b2 * 16));
      #pragma unroll
      for (int e = 0; e < 8; ++e) { float fv = bf2f((unsigned short)vb[e]); v[b2*8+e] = fv; s1 += fv; }
    }
    s1 += __shfl_xor(s1, 1);
    s1 += __shfl_xor(s1, 2);
    float mu = s1 * (1.f / 256.f);
    float s2 = 0.f;
    #pragma unroll
    for (int e = 0; e < 64; ++e) { float d = v[e] - mu; s2 += d * d; }
    s2 += __shfl_xor(s2, 1);
    s2 += __shfl_xor(s2, 2);
    float rs = rsqrtf(s2 * (1.f / 256.f) + 1e-5f);
    #pragma unroll
    for (int e = 0; e < 64; ++e) {
      int c = q4 * 64 + e;
      float xwv = bf2f(*(const unsigned short*)(sm + L_XW + t * 512 + swzb(t, c * 2)));
      float yv = (v[e] - mu) * rs * ln1w[c] + ln1b[c] + xwv;
      *(unsigned short*)(sm + L_Y + t * 512 + swzb(t, c * 2)) = f2bf(yv);
    }
  }
  __syncthreads();

  // ---------- MLP: fc1(gelu) in 4 chunks, fc2 accumulated in registers ----------
  f32x4 acc2[4][4];
  #pragma unroll
  for (int a = 0; a < 4; ++a)
    #pragma unroll
    for (int b = 0; b < 4; ++b) acc2[a][b] = f32x4{0.f,0.f,0.f,0.f};

  #pragma unroll 1
  for (int cc = 0; cc < 4; ++cc) {
    f32x4 acc1[4][4];
    #pragma unroll
    for (int a = 0; a < 4; ++a)
      #pragma unroll
      for (int b = 0; b < 4; ++b) acc1[a][b] = f32x4{0.f,0.f,0.f,0.f};
    for (int k0 = 0; k0 < 256; k0 += 32) {
      s16x8 af[4];
      #pragma unroll
      for (int mt = 0; mt < 4; ++mt) {
        int row = mt * 16 + c16;
        af[mt] = *(const s16x8*)(sm + L_Y + row * 512 + swzb(row, (k0 + g * 8) * 2));
      }
      #pragma unroll
      for (int nt = 0; nt < 4; ++nt) {
        int gt = cc * 16 + w * 4 + nt;
        s16x8 bfr = *(const s16x8*)(fc1w + ((gt * 32 + (k0 >> 3) + g) * 16 + c16) * 8);
        #pragma unroll
        for (int mt = 0; mt < 4; ++mt)
          acc1[nt][mt] = __builtin_amdgcn_mfma_f32_16x16x32_bf16(af[mt], bfr, acc1[nt][mt], 0, 0, 0);
      }
    }
    #pragma unroll
    for (int nt = 0; nt < 4; ++nt) {
      int coll = w * 64 + nt * 16 + c16;
      float b1v = fc1b[cc * 256 + coll];
      #pragma unroll
      for (int mt = 0; mt < 4; ++mt)
        #pragma unroll
        for (int r = 0; r < 4; ++r) {
          int i = mt * 16 + 4 * g + r;
          float u = acc1[nt][mt][r] + b1v;
          float z = 0.7978845608f * u * (1.f + 0.044715f * u * u);
          float e2 = __expf(2.f * z);
          float ge = u * e2 / (e2 + 1.f);
          *(unsigned short*)(sm + L_H + i * 512 + swzb(i, coll * 2)) = f2bf(ge);
        }
    }
    __syncthreads();
    for (int k0 = 0; k0 < 256; k0 += 32) {
      s16x8 af[4];
      #pragma unroll
      for (int mt = 0; mt < 4; ++mt) {
        int row = mt * 16 + c16;
        af[mt] = *(const s16x8*)(sm + L_H + row * 512 + swzb(row, (k0 + g * 8) * 2));
      }
      #pragma unroll
      for (int nt = 0; nt < 4; ++nt) {
        int kg = cc * 32 + (k0 >> 3) + g;
        s16x8 bfr = *(const s16x8*)(fc2w + (((w * 4 + nt) * 128 + kg) * 16 + c16) * 8);
        #pragma unroll
        for (int mt = 0; mt < 4; ++mt)
          acc2[nt][mt] = __builtin_amdgcn_mfma_f32_16x16x32_bf16(af[mt], bfr, acc2[nt][mt], 0, 0, 0);
      }
    }
    __syncthreads();
  }

  // ---------- fc2 epilogue -> MB bf16 (aliases H) ----------
  #pragma unroll
  for (int nt = 0; nt < 4; ++nt) {
    int col = w * 64 + nt * 16 + c16;
    float b2v = fc2b[col];
    #pragma unroll
    for (int mt = 0; mt < 4; ++mt)
      #pragma unroll
      for (int r = 0; r < 4; ++r) {
        int i = mt * 16 + 4 * g + r;
        *(unsigned short*)(sm + L_MB + i * 512 + swzb(i, col * 2)) = f2bf(acc2[nt][mt][r] + b2v);
      }
  }
  __syncthreads();

  // ---------- LN2 + residual in registers, then direct store to sout ----------
  {
    int t2 = tid >> 2, q4 = tid & 3;
    float v[64];
    float s1 = 0.f;
    #pragma unroll
    for (int b2 = 0; b2 < 8; ++b2) {
      s16x8 vb = *(const s16x8*)(sm + L_MB + t2 * 512 + swzb(t2, q4 * 128 + b2 * 16));
      #pragma unroll
      for (int e = 0; e < 8; ++e) { float fv = bf2f((unsigned short)vb[e]); v[b2*8+e] = fv; s1 += fv; }
    }
    s1 += __shfl_xor(s1, 1);
    s1 += __shfl_xor(s1, 2);
    float mu = s1 * (1.f / 256.f);
    float s2 = 0.f;
    #pragma unroll
    for (int e = 0; e < 64; ++e) { float d = v[e] - mu; s2 += d * d; }
    s2 += __shfl_xor(s2, 1);
    s2 += __shfl_xor(s2, 2);
    float rs = rsqrtf(s2 * (1.f / 256.f) + 1e-5f);
    #pragma unroll
    for (int e = 0; e < 64; ++e) {
      int c = q4 * 64 + e;
      float yres = bf2f(*(const unsigned short*)(sm + L_Y + t2 * 512 + swzb(t2, c * 2)));
      v[e] = (v[e] - mu) * rs * ln2w[c] + ln2b[c] + yres;
    }
    // direct bf16 store: token t2, channels q4*64..q4*64+63 (128B contiguous per lane)
    int rp = (wi * 8 + (t2 >> 3) + 4) & 255;
    int cp = (wj * 8 + (t2 & 7) + 4) & 255;
    size_t pix = (size_t)bb * 65536 + rp * 256 + cp;
    unsigned short* so = sout + pix * 256 + q4 * 64;
    #pragma unroll
    for (int e8 = 0; e8 < 8; ++e8) {
      s16x8 pk;
      #pragma unroll
      for (int j = 0; j < 8; ++j) pk[j] = (short)f2bf(v[e8 * 8 + j]);
      *(s16x8*)(so + e8 * 8) = pk;
    }
  }
}

extern "C" void kernel_launch(void* const* d_in, const int* in_sizes, int n_in,
                              void* d_out, int out_size, void* d_ws, size_t ws_size,
                              hipStream_t stream) {
  const float* x      = (const float*)d_in[0];
  const float* qkv_w  = (const float*)d_in[1];
  const float* ls     = (const float*)d_in[2];
  const float* proj_w = (const float*)d_in[3];
  const float* proj_b = (const float*)d_in[4];
  const float* ln1w   = (const float*)d_in[5];
  const float* ln1b   = (const float*)d_in[6];
  const float* fc1_w  = (const float*)d_in[7];
  const float* fc1b   = (const float*)d_in[8];
  const float* fc2_w  = (const float*)d_in[9];
  const float* fc2b   = (const float*)d_in[10];
  const float* ln2w   = (const float*)d_in[11];
  const float* ln2b   = (const float*)d_in[12];
  const float* cpb_w1 = (const float*)d_in[13];
  const float* cpb_b1 = (const float*)d_in[14];
  const float* cpb_w2 = (const float*)d_in[15];
  unsigned char* wsb = (unsigned char*)d_ws;
  float* out = (float*)d_out;

  hipFuncSetAttribute(reinterpret_cast<const void*>(swin_block_kernel),
                      hipFuncAttributeMaxDynamicSharedMemorySize, SMEM_BYTES);

  prep_pack_kernel<<<3072, 256, 0, stream>>>(qkv_w, proj_w, fc1_w, fc2_w, wsb);
  prep_bias_kernel<<<1, 256, 0, stream>>>(cpb_w1, cpb_b1, cpb_w2, wsb);
  transpose_in_kernel<<<8192, 256, 0, stream>>>(x, wsb);
  swin_block_kernel<<<2048, 256, SMEM_BYTES, stream>>>(
      ls, proj_b, ln1w, ln1b, fc1b, fc2b, ln2w, ln2b, wsb);
  transpose_out_kernel<<<8192, 256, 0, stream>>>(wsb, out);
}

// Round 4
// 1013.582 us; speedup vs baseline: 1.4915x; 1.3567x over previous
//
#include <hip/hip_runtime.h>

typedef __attribute__((ext_vector_type(4))) float f32x4;
typedef __attribute__((ext_vector_type(8))) short s16x8;

// ---- LDS layout (byte offsets), total 73728 B -> 2 blocks/CU ----
#define L_XW   0        // bf16 [64][256] swz, stride 512B  (later: H chunk, mlp bf16)
#define L_QK   32768    // bf16 [2][64][64] (q cols 0-31 | k cols 32-63), stride 128B/row
#define L_VT   49152    // bf16 [2][32][64] v transposed, stride 128B
#define L_P    57344    // bf16 [64][64], stride 128B
#define L_OS   65536    // bf16 [2][64][32] per-head O slice, stride 64B
#define L_Y    32768    // bf16 [64][256] swz, stride 512B (aliases QK/VT/P after attention)
#define L_H    0        // bf16 [64][256] (aliases XW after LN1)
#define L_MB   0        // bf16 [64][256] mlp pre-LN (aliases H after fc2)
#define SMEM_BYTES 73728

// ---- workspace layout (byte offsets) ----
#define WSO_BIAS   0          // f32 [8][64][16][4] packed (h,i,c16,nt)   131072 B
#define WSO_QKVW   131072     // bf16 [48][32][16][8]       393216 B
#define WSO_PROJW  524288     // bf16 [16][32][16][8]       131072 B
#define WSO_FC1W   655360     // bf16 [64][32][16][8]       524288 B
#define WSO_FC2W   1179648    // bf16 [16][128][16][8]      524288 B
#define WSO_SIN    1703936ULL // bf16 [2][65536][256]       67108864 B
#define WSO_SOUT   68812800ULL// bf16 [2][65536][256]       67108864 B  (ends ~136 MB)

__device__ __forceinline__ unsigned short f2bf(float f) {
  union { float f; unsigned u; } v; v.f = f;
  unsigned r = v.u + 0x7FFFu + ((v.u >> 16) & 1u);
  return (unsigned short)(r >> 16);
}
__device__ __forceinline__ float bf2f(unsigned short b) {
  union { unsigned u; float f; } v; v.u = ((unsigned)b) << 16;
  return v.f;
}
__device__ __forceinline__ int swzb(int row, int byteoff) {  // for rows >=128B
  return byteoff ^ ((row & 7) << 4);
}
__device__ __forceinline__ int swz64(int row, int byteoff) { // for 64B rows
  return byteoff ^ ((row & 3) << 4);
}

// ---------------- prep: pack all weights to bf16 MFMA-fragment layout ----------------
__global__ void prep_pack_kernel(const float* __restrict__ qkv_w,
                                 const float* __restrict__ proj_w,
                                 const float* __restrict__ fc1_w,
                                 const float* __restrict__ fc2_w,
                                 unsigned char* __restrict__ wsb) {
  int e = blockIdx.x * 256 + threadIdx.x;   // 0 .. 786431
  const float* src; unsigned short* dst; int K, N; int eo;
  if (e < 196608)       { eo = e;          src = qkv_w;  dst = (unsigned short*)(wsb + WSO_QKVW);  K = 256;  N = 768; }
  else if (e < 262144)  { eo = e - 196608; src = proj_w; dst = (unsigned short*)(wsb + WSO_PROJW); K = 256;  N = 256; }
  else if (e < 524288)  { eo = e - 262144; src = fc1_w;  dst = (unsigned short*)(wsb + WSO_FC1W);  K = 256;  N = 1024; }
  else                  { eo = e - 524288; src = fc2_w;  dst = (unsigned short*)(wsb + WSO_FC2W);  K = 1024; N = 256; }
  int j = eo & 7, c = (eo >> 3) & 15, rest = eo >> 7;
  int Kg = K >> 3;
  int kg = rest % Kg, nt = rest / Kg;
  dst[eo] = f2bf(src[(kg * 8 + j) * N + nt * 16 + c]);
}

// ---------------- prep: relative-position-bias table via CPB MLP (packed float4) ----------------
__global__ void prep_bias_kernel(const float* __restrict__ cpb_w1,
                                 const float* __restrict__ cpb_b1,
                                 const float* __restrict__ cpb_w2,
                                 unsigned char* __restrict__ wsb) {
  __shared__ float bt[225][8];
  int tid = threadIdx.x;
  for (int t = tid; t < 225; t += 256) {
    int a = t / 15, b = t % 15;
    float r0 = (float)(a - 7) * (8.0f / 7.0f);
    float r1 = (float)(b - 7) * (8.0f / 7.0f);
    float f0 = (r0 >= 0.f ? 1.f : -1.f) * log2f(fabsf(r0) + 1.f) * (1.f / 3.f);
    float f1 = (r1 >= 0.f ? 1.f : -1.f) * log2f(fabsf(r1) + 1.f) * (1.f / 3.f);
    float acc[8] = {0.f,0.f,0.f,0.f,0.f,0.f,0.f,0.f};
    for (int k = 0; k < 512; ++k) {
      float hv = f0 * cpb_w1[k] + f1 * cpb_w1[512 + k] + cpb_b1[k];
      hv = fmaxf(hv, 0.f);
      #pragma unroll
      for (int h = 0; h < 8; ++h) acc[h] += hv * cpb_w2[k * 8 + h];
    }
    #pragma unroll
    for (int h = 0; h < 8; ++h) bt[t][h] = acc[h];
  }
  __syncthreads();
  float* biasp = (float*)(wsb + WSO_BIAS);
  for (int e = tid; e < 32768; e += 256) {
    int nn = e & 3, cc = (e >> 2) & 15, i = (e >> 6) & 63, h = e >> 12;
    int j = nn * 16 + cc;
    int dr = (i >> 3) - (j >> 3) + 7, dc = (i & 7) - (j & 7) + 7;
    float v = bt[dr * 15 + dc][h];
    biasp[e] = 16.f / (1.f + expf(-v));
  }
}

// ---------------- pass A: x[b][c][p] f32 -> sin[b][p][c] bf16 (tiled transpose) ----------------
__global__ __launch_bounds__(256)
void transpose_in_kernel(const float* __restrict__ x, unsigned char* __restrict__ wsb) {
  __shared__ float tile[64][65];
  int pb = blockIdx.x & 1023;
  int cg = (blockIdx.x >> 10) & 3;
  int b  = blockIdx.x >> 12;
  int p0 = pb * 64, c0 = cg * 64;
  int tid = threadIdx.x;
  unsigned short* sg = (unsigned short*)(wsb + WSO_SIN);

  int pi = tid & 63, cq = tid >> 6;       // read: 4 c-rows per iter, coalesced along p
  for (int r = 0; r < 16; ++r) {
    int c = cq * 16 + r;
    tile[pi][c] = x[((size_t)(b * 256 + c0 + c)) * 65536 + p0 + pi];
  }
  __syncthreads();
  int po = tid >> 2, co = tid & 3;        // write: 32B per thread, coalesced along c
  s16x8 pk0, pk1;
  #pragma unroll
  for (int j = 0; j < 8; ++j) {
    pk0[j] = (short)f2bf(tile[po][co * 16 + j]);
    pk1[j] = (short)f2bf(tile[po][co * 16 + 8 + j]);
  }
  unsigned short* dp = sg + ((size_t)b * 65536 + p0 + po) * 256 + c0 + co * 16;
  *(s16x8*)(dp) = pk0;
  *(s16x8*)(dp + 8) = pk1;
}

// ---------------- pass B: sout[b][p][c] bf16 -> out[b][c][p] f32 (tiled transpose) ----------------
__global__ __launch_bounds__(256)
void transpose_out_kernel(const unsigned char* __restrict__ wsb, float* __restrict__ out) {
  __shared__ float tile[64][65];
  int pb = blockIdx.x & 1023;
  int cg = (blockIdx.x >> 10) & 3;
  int b  = blockIdx.x >> 12;
  int p0 = pb * 64, c0 = cg * 64;
  int tid = threadIdx.x;
  const unsigned short* sg = (const unsigned short*)(wsb + WSO_SOUT);

  int pi = tid >> 2, cq = tid & 3;        // read: 32B per thread, coalesced along c
  const unsigned short* rp = sg + ((size_t)b * 65536 + p0 + pi) * 256 + c0 + cq * 16;
  s16x8 a0 = *(const s16x8*)(rp);
  s16x8 a1 = *(const s16x8*)(rp + 8);
  #pragma unroll
  for (int j = 0; j < 8; ++j) {
    tile[pi][cq * 16 + j]     = bf2f((unsigned short)a0[j]);
    tile[pi][cq * 16 + 8 + j] = bf2f((unsigned short)a1[j]);
  }
  __syncthreads();
  int ci = tid >> 6, pi2 = tid & 63;      // write: coalesced along p
  for (int r = 0; r < 16; ++r) {
    int c = ci * 16 + r;
    out[((size_t)(b * 256 + c0 + c)) * 65536 + p0 + pi2] = tile[pi2][c];
  }
}

// ---------------- main fused per-window kernel ----------------
// __launch_bounds__(256, 1): evidence (round 1 vs rounds 2-3) shows the ,2 variant
// caps VGPR at 128 and demotes the MFMA accumulator arrays to scratch (~1.6 GB of
// spill traffic). At 256 VGPR/wave the hardware still allows 8 waves/CU, so the
// 72 KB LDS footprint (2 blocks/CU) remains the occupancy limiter — same occupancy,
// no spills.
__global__ __launch_bounds__(256, 1)
void swin_block_kernel(const float* __restrict__ ls,
                       const float* __restrict__ proj_b,
                       const float* __restrict__ ln1w, const float* __restrict__ ln1b,
                       const float* __restrict__ fc1b,
                       const float* __restrict__ fc2b,
                       const float* __restrict__ ln2w, const float* __restrict__ ln2b,
                       unsigned char* __restrict__ wsb) {
  extern __shared__ char sm[];
  const int tid = threadIdx.x;
  const int w = tid >> 6;
  const int lane = tid & 63;
  const int g = lane >> 4;
  const int c16 = lane & 15;

  const int blk = blockIdx.x;
  const int bb = blk >> 10;
  const int widx = blk & 1023;
  const int wi = widx >> 5, wj = widx & 31;

  const f32x4* biasv = (const f32x4*)(wsb + WSO_BIAS);
  const unsigned short* qkvw = (const unsigned short*)(wsb + WSO_QKVW);
  const unsigned short* projw = (const unsigned short*)(wsb + WSO_PROJW);
  const unsigned short* fc1w = (const unsigned short*)(wsb + WSO_FC1W);
  const unsigned short* fc2w = (const unsigned short*)(wsb + WSO_FC2W);
  const unsigned short* sin_ = (const unsigned short*)(wsb + WSO_SIN);
  unsigned short* sout = (unsigned short*)(wsb + WSO_SOUT);

  // ---------- Phase 1: copy window from sin (channel-contiguous) -> XW bf16 swz ----------
  #pragma unroll
  for (int it = 0; it < 8; ++it) {
    int u = tid + it * 256;              // 16B units: u = t*32 + cu
    int t = u >> 5, cu = u & 31;
    int rp = (wi * 8 + (t >> 3) + 4) & 255;
    int cp = (wj * 8 + (t & 7) + 4) & 255;
    size_t pix = (size_t)bb * 65536 + rp * 256 + cp;
    s16x8 v = *(const s16x8*)(sin_ + pix * 256 + cu * 8);
    *(s16x8*)(sm + L_XW + t * 512 + swzb(t, cu * 16)) = v;
  }
  __syncthreads();

  // persistent proj accumulator (built incrementally per head)
  f32x4 accP[4][4];
  #pragma unroll
  for (int a = 0; a < 4; ++a)
    #pragma unroll
    for (int b = 0; b < 4; ++b) accP[a][b] = f32x4{0.f,0.f,0.f,0.f};

  // ---------- attention (+fused proj) per head pair ----------
  #pragma unroll 1
  for (int hp = 0; hp < 4; ++hp) {
    f32x4 acc[3][4];
    #pragma unroll
    for (int a = 0; a < 3; ++a)
      #pragma unroll
      for (int b = 0; b < 4; ++b) acc[a][b] = f32x4{0.f,0.f,0.f,0.f};
    int gtile[3];
    #pragma unroll
    for (int tl = 0; tl < 3; ++tl) {
      int local = w * 3 + tl;
      int kind = local >> 2, sub = local & 3;
      int hh = sub >> 1, dt = sub & 1;
      gtile[tl] = kind * 16 + (2 * hp + hh) * 2 + dt;
    }
    for (int k0 = 0; k0 < 256; k0 += 32) {
      s16x8 af[4];
      #pragma unroll
      for (int mt = 0; mt < 4; ++mt) {
        int row = mt * 16 + c16;
        af[mt] = *(const s16x8*)(sm + L_XW + row * 512 + swzb(row, (k0 + g * 8) * 2));
      }
      #pragma unroll
      for (int tl = 0; tl < 3; ++tl) {
        s16x8 bfr = *(const s16x8*)(qkvw + ((gtile[tl] * 32 + (k0 >> 3) + g) * 16 + c16) * 8);
        #pragma unroll
        for (int mt = 0; mt < 4; ++mt)
          acc[tl][mt] = __builtin_amdgcn_mfma_f32_16x16x32_bf16(af[mt], bfr, acc[tl][mt], 0, 0, 0);
      }
    }
    // epilogue: q,k -> QK[hh]; v -> VT[hh] transposed
    #pragma unroll
    for (int tl = 0; tl < 3; ++tl) {
      int local = w * 3 + tl;
      int kind = local >> 2, sub = local & 3;
      int hh = sub >> 1, dt = sub & 1;
      #pragma unroll
      for (int mt = 0; mt < 4; ++mt)
        #pragma unroll
        for (int r = 0; r < 4; ++r) {
          int i = mt * 16 + 4 * g + r;
          unsigned short bv = f2bf(acc[tl][mt][r]);
          if (kind == 0) {
            *(unsigned short*)(sm + L_QK + hh * 8192 + i * 128 + swzb(i, (dt * 16 + c16) * 2)) = bv;
          } else if (kind == 1) {
            *(unsigned short*)(sm + L_QK + hh * 8192 + i * 128 + swzb(i, 64 + (dt * 16 + c16) * 2)) = bv;
          } else {
            int d = dt * 16 + c16;
            *(unsigned short*)(sm + L_VT + hh * 4096 + d * 128 + swzb(d, i * 2)) = bv;
          }
        }
    }
    __syncthreads();

    // cosine-normalize q (with logit scale) and k, in place
    {
      int hh2 = tid >> 7, qi = (tid >> 6) & 1, t = tid & 63;
      char* base = sm + L_QK + hh2 * 8192 + t * 128;
      float vals[32];
      float ss = 0.f;
      #pragma unroll
      for (int b = 0; b < 4; ++b) {
        s16x8 vb = *(const s16x8*)(base + swzb(t, qi * 64 + b * 16));
        #pragma unroll
        for (int e = 0; e < 8; ++e) { float fv = bf2f((unsigned short)vb[e]); vals[b*8+e] = fv; ss += fv * fv; }
      }
      float scale = 1.f;
      if (qi == 0) scale = __expf(fminf(ls[2 * hp + hh2], 4.6051702f));
      float inv = scale / fmaxf(sqrtf(ss), 1e-12f);
      #pragma unroll
      for (int b = 0; b < 4; ++b) {
        s16x8 vb;
        #pragma unroll
        for (int e = 0; e < 8; ++e) vb[e] = (short)f2bf(vals[b*8+e] * inv);
        *(s16x8*)(base + swzb(t, qi * 64 + b * 16)) = vb;
      }
    }
    __syncthreads();

    #pragma unroll 1
    for (int hh = 0; hh < 2; ++hh) {
      int h = 2 * hp + hh;
      f32x4 bb4[4];
      #pragma unroll
      for (int r = 0; r < 4; ++r) {
        int i = 16 * w + 4 * g + r;
        bb4[r] = biasv[(h * 64 + i) * 16 + c16];
      }
      int arow = 16 * w + c16;
      s16x8 aq = *(const s16x8*)(sm + L_QK + hh * 8192 + arow * 128 + swzb(arow, g * 16));
      f32x4 s[4];
      #pragma unroll
      for (int nt = 0; nt < 4; ++nt) {
        int brow = nt * 16 + c16;
        s16x8 bk = *(const s16x8*)(sm + L_QK + hh * 8192 + brow * 128 + swzb(brow, 64 + g * 16));
        s[nt] = __builtin_amdgcn_mfma_f32_16x16x32_bf16(aq, bk, f32x4{0.f,0.f,0.f,0.f}, 0, 0, 0);
      }
      int labi[4], labj[4];
      #pragma unroll
      for (int r = 0; r < 4; ++r) {
        int i = 16 * w + 4 * g + r;
        int tr = i >> 3, tc = i & 7;
        labi[r] = ((wi == 31) ? (tr >= 4 ? 2 : 1) : 0) * 3 + ((wj == 31) ? (tc >= 4 ? 2 : 1) : 0);
      }
      #pragma unroll
      for (int nt = 0; nt < 4; ++nt) {
        int j = nt * 16 + c16;
        int tr = j >> 3, tc = j & 7;
        labj[nt] = ((wi == 31) ? (tr >= 4 ? 2 : 1) : 0) * 3 + ((wj == 31) ? (tc >= 4 ? 2 : 1) : 0);
      }
      float p[4][4];
      #pragma unroll
      for (int r = 0; r < 4; ++r) {
        float mx = -1e30f;
        float vv[4];
        #pragma unroll
        for (int nt = 0; nt < 4; ++nt) {
          float v = s[nt][r] + bb4[r][nt];
          if (labi[r] != labj[nt]) v -= 100.f;
          vv[nt] = v;
          mx = fmaxf(mx, v);
        }
        mx = fmaxf(mx, __shfl_xor(mx, 1));
        mx = fmaxf(mx, __shfl_xor(mx, 2));
        mx = fmaxf(mx, __shfl_xor(mx, 4));
        mx = fmaxf(mx, __shfl_xor(mx, 8));
        float sum = 0.f;
        #pragma unroll
        for (int nt = 0; nt < 4; ++nt) { vv[nt] = __expf(vv[nt] - mx); sum += vv[nt]; }
        sum += __shfl_xor(sum, 1);
        sum += __shfl_xor(sum, 2);
        sum += __shfl_xor(sum, 4);
        sum += __shfl_xor(sum, 8);
        float inv = 1.f / sum;
        #pragma unroll
        for (int nt = 0; nt < 4; ++nt) p[nt][r] = vv[nt] * inv;
      }
      #pragma unroll
      for (int nt = 0; nt < 4; ++nt)
        #pragma unroll
        for (int r = 0; r < 4; ++r) {
          int i = 16 * w + 4 * g + r;
          int j = nt * 16 + c16;
          *(unsigned short*)(sm + L_P + i * 128 + swzb(i, j * 2)) = f2bf(p[nt][r]);
        }
      __syncthreads();   // B1: P complete

      f32x4 oacc[2] = {f32x4{0.f,0.f,0.f,0.f}, f32x4{0.f,0.f,0.f,0.f}};
      #pragma unroll
      for (int k0 = 0; k0 < 64; k0 += 32) {
        int prow = 16 * w + c16;
        s16x8 pa = *(const s16x8*)(sm + L_P + prow * 128 + swzb(prow, (k0 + g * 8) * 2));
        #pragma unroll
        for (int nt = 0; nt < 2; ++nt) {
          int vrow = nt * 16 + c16;
          s16x8 vb = *(const s16x8*)(sm + L_VT + hh * 4096 + vrow * 128 + swzb(vrow, (k0 + g * 8) * 2));
          oacc[nt] = __builtin_amdgcn_mfma_f32_16x16x32_bf16(pa, vb, oacc[nt], 0, 0, 0);
        }
      }
      #pragma unroll
      for (int nt = 0; nt < 2; ++nt)
        #pragma unroll
        for (int r = 0; r < 4; ++r) {
          int i = 16 * w + 4 * g + r;
          int d = nt * 16 + c16;
          *(unsigned short*)(sm + L_OS + hh * 4096 + i * 64 + swz64(i, d * 2)) = f2bf(oacc[nt][r]);
        }
      __syncthreads();   // B2: O slice complete

      s16x8 paf[4];
      #pragma unroll
      for (int mt = 0; mt < 4; ++mt) {
        int row = mt * 16 + c16;
        paf[mt] = *(const s16x8*)(sm + L_OS + hh * 4096 + row * 64 + swz64(row, g * 16));
      }
      #pragma unroll
      for (int nt = 0; nt < 4; ++nt) {
        s16x8 bfr = *(const s16x8*)(projw + (((w * 4 + nt) * 32 + h * 4 + g) * 16 + c16) * 8);
        #pragma unroll
        for (int mt = 0; mt < 4; ++mt)
          accP[nt][mt] = __builtin_amdgcn_mfma_f32_16x16x32_bf16(paf[mt], bfr, accP[nt][mt], 0, 0, 0);
      }
    }
  }

  // ---------- proj epilogue: o + proj_b -> Y (bf16, over QK/VT/P region) ----------
  #pragma unroll
  for (int nt = 0; nt < 4; ++nt) {
    int col = w * 64 + nt * 16 + c16;
    float pb = proj_b[col];
    #pragma unroll
    for (int mt = 0; mt < 4; ++mt)
      #pragma unroll
      for (int r = 0; r < 4; ++r) {
        int i = mt * 16 + 4 * g + r;
        *(unsigned short*)(sm + L_Y + i * 512 + swzb(i, col * 2)) = f2bf(accP[nt][mt][r] + pb);
      }
  }
  __syncthreads();

  // ---------- LN1 + residual: y = LN(o)*g+b + xw, in place on Y (bf16) ----------
  {
    int t = tid >> 2, q4 = tid & 3;
    float v[64];
    float s1 = 0.f;
    #pragma unroll
    for (int b2 = 0; b2 < 8; ++b2) {
      s16x8 vb = *(const s16x8*)(sm + L_Y + t * 512 + swzb(t, q4 * 128 + b2 * 16));
      #pragma unroll
      for (int e = 0; e < 8; ++e) { float fv = bf2f((unsigned short)vb[e]); v[b2*8+e] = fv; s1 += fv; }
    }
    s1 += __shfl_xor(s1, 1);
    s1 += __shfl_xor(s1, 2);
    float mu = s1 * (1.f / 256.f);
    float s2 = 0.f;
    #pragma unroll
    for (int e = 0; e < 64; ++e) { float d = v[e] - mu; s2 += d * d; }
    s2 += __shfl_xor(s2, 1);
    s2 += __shfl_xor(s2, 2);
    float rs = rsqrtf(s2 * (1.f / 256.f) + 1e-5f);
    #pragma unroll
    for (int e = 0; e < 64; ++e) {
      int c = q4 * 64 + e;
      float xwv = bf2f(*(const unsigned short*)(sm + L_XW + t * 512 + swzb(t, c * 2)));
      float yv = (v[e] - mu) * rs * ln1w[c] + ln1b[c] + xwv;
      *(unsigned short*)(sm + L_Y + t * 512 + swzb(t, c * 2)) = f2bf(yv);
    }
  }
  __syncthreads();

  // ---------- MLP: fc1(gelu) in 4 chunks, fc2 accumulated in registers ----------
  f32x4 acc2[4][4];
  #pragma unroll
  for (int a = 0; a < 4; ++a)
    #pragma unroll
    for (int b = 0; b < 4; ++b) acc2[a][b] = f32x4{0.f,0.f,0.f,0.f};

  #pragma unroll 1
  for (int cc = 0; cc < 4; ++cc) {
    f32x4 acc1[4][4];
    #pragma unroll
    for (int a = 0; a < 4; ++a)
      #pragma unroll
      for (int b = 0; b < 4; ++b) acc1[a][b] = f32x4{0.f,0.f,0.f,0.f};
    for (int k0 = 0; k0 < 256; k0 += 32) {
      s16x8 af[4];
      #pragma unroll
      for (int mt = 0; mt < 4; ++mt) {
        int row = mt * 16 + c16;
        af[mt] = *(const s16x8*)(sm + L_Y + row * 512 + swzb(row, (k0 + g * 8) * 2));
      }
      #pragma unroll
      for (int nt = 0; nt < 4; ++nt) {
        int gt = cc * 16 + w * 4 + nt;
        s16x8 bfr = *(const s16x8*)(fc1w + ((gt * 32 + (k0 >> 3) + g) * 16 + c16) * 8);
        #pragma unroll
        for (int mt = 0; mt < 4; ++mt)
          acc1[nt][mt] = __builtin_amdgcn_mfma_f32_16x16x32_bf16(af[mt], bfr, acc1[nt][mt], 0, 0, 0);
      }
    }
    #pragma unroll
    for (int nt = 0; nt < 4; ++nt) {
      int coll = w * 64 + nt * 16 + c16;
      float b1v = fc1b[cc * 256 + coll];
      #pragma unroll
      for (int mt = 0; mt < 4; ++mt)
        #pragma unroll
        for (int r = 0; r < 4; ++r) {
          int i = mt * 16 + 4 * g + r;
          float u = acc1[nt][mt][r] + b1v;
          float z = 0.7978845608f * u * (1.f + 0.044715f * u * u);
          float e2 = __expf(2.f * z);
          float ge = u * e2 / (e2 + 1.f);
          *(unsigned short*)(sm + L_H + i * 512 + swzb(i, coll * 2)) = f2bf(ge);
        }
    }
    __syncthreads();
    for (int k0 = 0; k0 < 256; k0 += 32) {
      s16x8 af[4];
      #pragma unroll
      for (int mt = 0; mt < 4; ++mt) {
        int row = mt * 16 + c16;
        af[mt] = *(const s16x8*)(sm + L_H + row * 512 + swzb(row, (k0 + g * 8) * 2));
      }
      #pragma unroll
      for (int nt = 0; nt < 4; ++nt) {
        int kg = cc * 32 + (k0 >> 3) + g;
        s16x8 bfr = *(const s16x8*)(fc2w + (((w * 4 + nt) * 128 + kg) * 16 + c16) * 8);
        #pragma unroll
        for (int mt = 0; mt < 4; ++mt)
          acc2[nt][mt] = __builtin_amdgcn_mfma_f32_16x16x32_bf16(af[mt], bfr, acc2[nt][mt], 0, 0, 0);
      }
    }
    __syncthreads();
  }

  // ---------- fc2 epilogue -> MB bf16 (aliases H) ----------
  #pragma unroll
  for (int nt = 0; nt < 4; ++nt) {
    int col = w * 64 + nt * 16 + c16;
    float b2v = fc2b[col];
    #pragma unroll
    for (int mt = 0; mt < 4; ++mt)
      #pragma unroll
      for (int r = 0; r < 4; ++r) {
        int i = mt * 16 + 4 * g + r;
        *(unsigned short*)(sm + L_MB + i * 512 + swzb(i, col * 2)) = f2bf(acc2[nt][mt][r] + b2v);
      }
  }
  __syncthreads();

  // ---------- LN2 + residual in registers, then direct store to sout ----------
  {
    int t2 = tid >> 2, q4 = tid & 3;
    float v[64];
    float s1 = 0.f;
    #pragma unroll
    for (int b2 = 0; b2 < 8; ++b2) {
      s16x8 vb = *(const s16x8*)(sm + L_MB + t2 * 512 + swzb(t2, q4 * 128 + b2 * 16));
      #pragma unroll
      for (int e = 0; e < 8; ++e) { float fv = bf2f((unsigned short)vb[e]); v[b2*8+e] = fv; s1 += fv; }
    }
    s1 += __shfl_xor(s1, 1);
    s1 += __shfl_xor(s1, 2);
    float mu = s1 * (1.f / 256.f);
    float s2 = 0.f;
    #pragma unroll
    for (int e = 0; e < 64; ++e) { float d = v[e] - mu; s2 += d * d; }
    s2 += __shfl_xor(s2, 1);
    s2 += __shfl_xor(s2, 2);
    float rs = rsqrtf(s2 * (1.f / 256.f) + 1e-5f);
    #pragma unroll
    for (int e = 0; e < 64; ++e) {
      int c = q4 * 64 + e;
      float yres = bf2f(*(const unsigned short*)(sm + L_Y + t2 * 512 + swzb(t2, c * 2)));
      v[e] = (v[e] - mu) * rs * ln2w[c] + ln2b[c] + yres;
    }
    // direct bf16 store: token t2, channels q4*64..q4*64+63 (128B contiguous per lane)
    int rp = (wi * 8 + (t2 >> 3) + 4) & 255;
    int cp = (wj * 8 + (t2 & 7) + 4) & 255;
    size_t pix = (size_t)bb * 65536 + rp * 256 + cp;
    unsigned short* so = sout + pix * 256 + q4 * 64;
    #pragma unroll
    for (int e8 = 0; e8 < 8; ++e8) {
      s16x8 pk;
      #pragma unroll
      for (int j = 0; j < 8; ++j) pk[j] = (short)f2bf(v[e8 * 8 + j]);
      *(s16x8*)(so + e8 * 8) = pk;
    }
  }
}

extern "C" void kernel_launch(void* const* d_in, const int* in_sizes, int n_in,
                              void* d_out, int out_size, void* d_ws, size_t ws_size,
                              hipStream_t stream) {
  const float* x      = (const float*)d_in[0];
  const float* qkv_w  = (const float*)d_in[1];
  const float* ls     = (const float*)d_in[2];
  const float* proj_w = (const float*)d_in[3];
  const float* proj_b = (const float*)d_in[4];
  const float* ln1w   = (const float*)d_in[5];
  const float* ln1b   = (const float*)d_in[6];
  const float* fc1_w  = (const float*)d_in[7];
  const float* fc1b   = (const float*)d_in[8];
  const float* fc2_w  = (const float*)d_in[9];
  const float* fc2b   = (const float*)d_in[10];
  const float* ln2w   = (const float*)d_in[11];
  const float* ln2b   = (const float*)d_in[12];
  const float* cpb_w1 = (const float*)d_in[13];
  const float* cpb_b1 = (const float*)d_in[14];
  const float* cpb_w2 = (const float*)d_in[15];
  unsigned char* wsb = (unsigned char*)d_ws;
  float* out = (float*)d_out;

  hipFuncSetAttribute(reinterpret_cast<const void*>(swin_block_kernel),
                      hipFuncAttributeMaxDynamicSharedMemorySize, SMEM_BYTES);

  prep_pack_kernel<<<3072, 256, 0, stream>>>(qkv_w, proj_w, fc1_w, fc2_w, wsb);
  prep_bias_kernel<<<1, 256, 0, stream>>>(cpb_w1, cpb_b1, cpb_w2, wsb);
  transpose_in_kernel<<<8192, 256, 0, stream>>>(x, wsb);
  swin_block_kernel<<<2048, 256, SMEM_BYTES, stream>>>(
      ls, proj_b, ln1w, ln1b, fc1b, fc2b, ln2w, ln2b, wsb);
  transpose_out_kernel<<<8192, 256, 0, stream>>>(wsb, out);
}